// Round 18
// baseline (131.459 us; speedup 1.0000x reference)
//
#include <hip/hip_runtime.h>
#include <cstdint>
#include <cstddef>

#define BB 16
#define NN 4096
#define EE 131072
#define CIN 256
#define COUT 256
#define NCH 16
#define CHE (EE / NCH)   // 8192 edges per chunk

typedef __attribute__((ext_vector_type(8))) _Float16 h16x8;
typedef __attribute__((ext_vector_type(4))) float f32x4;

// ---------------- phase A: hist (blocks 0..255) ∥ W^T->fp16 (256..511) ----------------
__global__ __launch_bounds__(256) void phaseA_kernel(const float* __restrict__ W, _Float16* __restrict__ wt,
                                                     const int* __restrict__ ei, const float* __restrict__ ew,
                                                     int* __restrict__ chist, float* __restrict__ wdeg) {
    __shared__ int h[NN];       // 16 KB
    __shared__ float wh[NN];    // 16 KB
    int bid = blockIdx.x;
    int tid = threadIdx.x;
    if (bid < BB * NCH) {
        int b = bid >> 4, c = bid & (NCH - 1);
        for (int i = tid; i < NN; i += 256) { h[i] = 0; wh[i] = 0.f; }
        __syncthreads();
        const int* rows = ei + (size_t)b * 2 * EE + (size_t)c * CHE;
        const float* w = ew + (size_t)b * EE + (size_t)c * CHE;
        #pragma unroll 4
        for (int j = 0; j < CHE / 256; ++j) {
            int row = rows[j * 256 + tid];
            float wv = w[j * 256 + tid];
            atomicAdd(&h[row], 1);
            atomicAdd(&wh[row], wv);
        }
        __syncthreads();
        int* co = chist + ((size_t)b * NCH + c) * NN;
        float* wo = wdeg + ((size_t)b * NCH + c) * NN;
        for (int i = tid; i < NN; i += 256) { co[i] = h[i]; wo[i] = wh[i]; }
    } else {
        int n = bid - BB * NCH;   // 0..255
        int k = tid;
        wt[n * CIN + k] = (_Float16)W[(size_t)k * COUT + n];
    }
}

// ---------------- fused: row totals + dinv + scan + per-chunk bases (16 blocks) ----------------
__global__ __launch_bounds__(1024) void scanfused_kernel(const int* __restrict__ chist, const float* __restrict__ wdeg,
                                                         int* __restrict__ chunkbase, int* __restrict__ roff,
                                                         float* __restrict__ dinv) {
    int b = blockIdx.x, tid = threadIdx.x;
    int wid = tid >> 6, lane = tid & 63;
    __shared__ int wsum[16];
    __shared__ int wbase[16];
    __shared__ int gtot_s;
    int carry = 0;
    for (int g = 0; g < 4; ++g) {
        int r = g * 1024 + tid;
        int cv[NCH];
        int tot = 0;
        float dsum = 1.0f;   // +1 self loop, always > 0
        #pragma unroll
        for (int c = 0; c < NCH; ++c) {
            size_t idx = ((size_t)b * NCH + c) * NN + r;
            cv[c] = chist[idx];
            tot += cv[c];
            dsum += wdeg[idx];
        }
        dinv[b * NN + r] = rsqrtf(dsum);
        int incl = tot;
        #pragma unroll
        for (int off = 1; off < 64; off <<= 1) {
            int t = __shfl_up(incl, off, 64);
            if (lane >= off) incl += t;
        }
        if (lane == 63) wsum[wid] = incl;
        __syncthreads();
        if (wid == 0) {
            int v = (lane < 16) ? wsum[lane] : 0;
            int winc = v;
            #pragma unroll
            for (int off = 1; off < 16; off <<= 1) {
                int t = __shfl_up(winc, off, 64);
                if (lane >= off) winc += t;
            }
            if (lane < 16) wbase[lane] = winc - v;
            if (lane == 15) gtot_s = winc;
        }
        __syncthreads();
        int excl = carry + wbase[wid] + (incl - tot);
        roff[b * NN + r] = excl;
        int acc = excl;
        #pragma unroll
        for (int c = 0; c < NCH; ++c) {
            chunkbase[((size_t)b * NCH + c) * NN + r] = acc;
            acc += cv[c];
        }
        carry += gtot_s;
        __syncthreads();
    }
}

// ---------------- scatter into packed CSR slots — LDS atomics only, XCD-pinned ----------------
__global__ __launch_bounds__(256) void scatter2_kernel(const int* __restrict__ ei, const float* __restrict__ ew,
                                                       const float* __restrict__ dinv, const int* __restrict__ chunkbase,
                                                       uint32_t* __restrict__ csr) {
    __shared__ int basebuf[NN];     // 16 KB
    __shared__ float dinvs[NN];     // 16 KB
    int bid = blockIdx.x;           // 256 blocks
    int xcd = bid & 7;
    int j = bid >> 3;
    int b = xcd * 2 + (j >> 4);
    int c = j & (NCH - 1);
    int tid = threadIdx.x;
    for (int i = tid; i < NN; i += 256) {
        basebuf[i] = chunkbase[((size_t)b * NCH + c) * NN + i];
        dinvs[i] = dinv[b * NN + i];
    }
    __syncthreads();
    const int* rows = ei + (size_t)b * 2 * EE + (size_t)c * CHE;
    const int* cols = rows + EE;
    const float* w = ew + (size_t)b * EE + (size_t)c * CHE;
    uint32_t* cs = csr + (size_t)b * EE;
    #pragma unroll 4
    for (int jj = 0; jj < CHE / 256; ++jj) {
        int e = jj * 256 + tid;
        int row = rows[e];
        int col = cols[e];
        float nm = dinvs[row] * w[e] * dinvs[col];
        int pos = atomicAdd(&basebuf[row], 1);
        uint32_t nmh = (uint32_t)__builtin_bit_cast(unsigned short, (_Float16)nm);
        cs[pos] = ((uint32_t)col << 16) | nmh;
    }
}

// ---------------- wide MFMA GEMM, 128x256 tile, 512 threads, XOR-swizzled LDS (FROZEN) ----------------
#define SWZ(byte_, row_) ((byte_) ^ (((row_) & 7) << 4))
__global__ __launch_bounds__(512) void gemm_wide_kernel(const float* __restrict__ x, const _Float16* __restrict__ wt,
                                                        _Float16* __restrict__ xw) {
    __shared__ __align__(16) char smem[49152];   // As 16 KB + Bs 32 KB
    char* As = smem;             // [128 rows][64 k] fp16, swizzled
    char* Bs = smem + 16384;     // [256 cols][64 k] fp16, swizzled
    int tid = threadIdx.x;
    int lane = tid & 63;
    int wid = tid >> 6;          // 0..7
    int wr = wid >> 2, wc = wid & 3;   // 2x4 wave grid, each wave 64 rows x 64 cols
    int hi = lane >> 4, lo = lane & 15;
    int row0 = blockIdx.x * 128; // 512 blocks
    f32x4 acc[4][4] = {};

    for (int kk = 0; kk < CIN; kk += 64) {
        #pragma unroll
        for (int j = 0; j < 2; ++j) {
            int c = j * 512 + tid;
            int r = c >> 3, kq = c & 7;
            const float* g = &x[(size_t)(row0 + r) * CIN + kk + 8 * kq];
            float4 f0 = *reinterpret_cast<const float4*>(g);
            float4 f1 = *reinterpret_cast<const float4*>(g + 4);
            h16x8 v;
            v[0] = (_Float16)f0.x; v[1] = (_Float16)f0.y; v[2] = (_Float16)f0.z; v[3] = (_Float16)f0.w;
            v[4] = (_Float16)f1.x; v[5] = (_Float16)f1.y; v[6] = (_Float16)f1.z; v[7] = (_Float16)f1.w;
            *reinterpret_cast<h16x8*>(As + SWZ(r * 128 + kq * 16, r)) = v;
        }
        #pragma unroll
        for (int j = 0; j < 4; ++j) {
            int c = j * 512 + tid;
            int r = c >> 3, kq = c & 7;
            *reinterpret_cast<h16x8*>(Bs + SWZ(r * 128 + kq * 16, r)) =
                *reinterpret_cast<const h16x8*>(&wt[(size_t)r * CIN + kk + 8 * kq]);
        }
        __syncthreads();
        #pragma unroll
        for (int ks = 0; ks < 2; ++ks) {
            h16x8 a[4], b[4];
            #pragma unroll
            for (int m = 0; m < 4; ++m) {
                int r = wr * 64 + m * 16 + lo;
                a[m] = *reinterpret_cast<const h16x8*>(As + SWZ(r * 128 + ks * 64 + hi * 16, r));
            }
            #pragma unroll
            for (int n = 0; n < 4; ++n) {
                int r = wc * 64 + n * 16 + lo;
                b[n] = *reinterpret_cast<const h16x8*>(Bs + SWZ(r * 128 + ks * 64 + hi * 16, r));
            }
            #pragma unroll
            for (int m = 0; m < 4; ++m)
                #pragma unroll
                for (int n = 0; n < 4; ++n)
                    acc[m][n] = __builtin_amdgcn_mfma_f32_16x16x32_f16(a[m], b[n], acc[m][n], 0, 0, 0);
        }
        __syncthreads();
    }
    #pragma unroll
    for (int m = 0; m < 4; ++m)
        #pragma unroll
        for (int n = 0; n < 4; ++n)
            #pragma unroll
            for (int r = 0; r < 4; ++r) {
                int row = row0 + wr * 64 + m * 16 + hi * 4 + r;
                int col = wc * 64 + n * 16 + lo;
                xw[(size_t)row * COUT + col] = (_Float16)acc[m][n][r];
            }
}

// ---------------- CSR aggregation v10: 2-stage s_load prefetch + and_or addr + fused asm block ----------------
// One asm block: 8 fma_mix, norm f16 from packed dword lo half, exact f32 accumulation.
#define ACCMIX8(w_, qv_) asm volatile( \
    "v_fma_mix_f32 %0, %8, %12, %0 op_sel:[0,0,0] op_sel_hi:[1,1,0]\n\t" \
    "v_fma_mix_f32 %1, %8, %12, %1 op_sel:[1,0,0] op_sel_hi:[1,1,0]\n\t" \
    "v_fma_mix_f32 %2, %9, %12, %2 op_sel:[0,0,0] op_sel_hi:[1,1,0]\n\t" \
    "v_fma_mix_f32 %3, %9, %12, %3 op_sel:[1,0,0] op_sel_hi:[1,1,0]\n\t" \
    "v_fma_mix_f32 %4, %10, %12, %4 op_sel:[0,0,0] op_sel_hi:[1,1,0]\n\t" \
    "v_fma_mix_f32 %5, %10, %12, %5 op_sel:[1,0,0] op_sel_hi:[1,1,0]\n\t" \
    "v_fma_mix_f32 %6, %11, %12, %6 op_sel:[0,0,0] op_sel_hi:[1,1,0]\n\t" \
    "v_fma_mix_f32 %7, %11, %12, %7 op_sel:[1,0,0] op_sel_hi:[1,1,0]" \
    : "+v"(a0), "+v"(a1), "+v"(a2), "+v"(a3), "+v"(a4), "+v"(a5), "+v"(a6), "+v"(a7) \
    : "v"((w_).x), "v"((w_).y), "v"((w_).z), "v"((w_).w), "v"(qv_))
#define MIXSLO(acc_, w_, nm_) asm("v_fma_mix_f32 %0, %1, %2, %0 op_sel:[0,0,0] op_sel_hi:[1,0,0]" \
                                  : "+v"(acc_) : "v"(w_), "v"(nm_));
#define MIXSHI(acc_, w_, nm_) asm("v_fma_mix_f32 %0, %1, %2, %0 op_sel:[1,0,0] op_sel_hi:[1,0,0]" \
                                  : "+v"(acc_) : "v"(w_), "v"(nm_));

__global__ __launch_bounds__(256) void aggregate_kernel(const _Float16* __restrict__ xw, const float* __restrict__ dinv,
                                                        const int* __restrict__ roff, const uint32_t* __restrict__ csr,
                                                        float* __restrict__ out) {
    int bid = blockIdx.x;            // 16384 blocks
    int xcd = bid & 7;
    int idx = bid >> 3;              // 0..2047
    int b = xcd * 2 + (idx >> 10);
    int rowblk = idx & 1023;
    int wave = threadIdx.x >> 6;
    int lane = threadIdx.x & 63;
    int n = rowblk * 4 + wave;       // 1 row per wave
    bool hiHalf = lane >= 32;
    int sub = lane & 31;             // 16B-granule index within row
    uint32_t lanebyte = sub * 16;    // bits 4..8

    const int* rb = roff + b * NN;
    int s = __builtin_amdgcn_readfirstlane(rb[n]);
    int eRaw = (n == NN - 1) ? EE : rb[n + 1];
    int e = __builtin_amdgcn_readfirstlane(eRaw);
    int cnt = e - s;
    const uint32_t* cs = csr + (size_t)b * EE + s;

    const char* xwbase = (const char*)(xw + (size_t)b * NN * COUT);   // wave-uniform base
    float a0 = 0.f, a1 = 0.f, a2 = 0.f, a3 = 0.f, a4 = 0.f, a5 = 0.f, a6 = 0.f, a7 = 0.f;

    {   // self loop (low half applies; high half nm=0, read harmless)
        float di = dinv[b * NN + n];
        float sn = hiHalf ? 0.f : di * di;
        uint4 w = *reinterpret_cast<const uint4*>(xwbase + (size_t)n * (COUT * 2) + lanebyte);
        MIXSLO(a0, w.x, sn); MIXSHI(a1, w.x, sn);
        MIXSLO(a2, w.y, sn); MIXSHI(a3, w.y, sn);
        MIXSLO(a4, w.z, sn); MIXSHI(a5, w.z, sn);
        MIXSLO(a6, w.w, sn); MIXSHI(a7, w.w, sn);
    }

    // addr math: col*512 = (qv >> 7) & 0x001FFE00 (bits 9..20); | lanebyte (bits 4..8) disjoint
    #define QOFF(qv_) ((((qv_) >> 7) & 0x001FFE00u) | lanebyte)

    int m = cnt & ~7;
    int i = 0;
    if (m >= 8) {
        uint32_t q0[8], q1[8];
        #pragma unroll
        for (int u = 0; u < 8; ++u) q0[u] = cs[u];       // scalar s_loads (wave-uniform)
        for (i = 8; i < m; i += 8) {
            #pragma unroll
            for (int u = 0; u < 8; ++u) q1[u] = cs[i + u];   // prefetch next chunk's CSR
            #pragma unroll
            for (int u = 0; u < 4; ++u) {
                uint32_t qv = hiHalf ? q0[2 * u + 1] : q0[2 * u];
                uint4 w = *reinterpret_cast<const uint4*>(xwbase + QOFF(qv));
                ACCMIX8(w, qv);
            }
            #pragma unroll
            for (int u = 0; u < 8; ++u) q0[u] = q1[u];
        }
        #pragma unroll
        for (int u = 0; u < 4; ++u) {
            uint32_t qv = hiHalf ? q0[2 * u + 1] : q0[2 * u];
            uint4 w = *reinterpret_cast<const uint4*>(xwbase + QOFF(qv));
            ACCMIX8(w, qv);
        }
    }
    if (m < cnt) {   // 1..7 remaining; pad with zeroed norm (clamped col keeps read in-bounds)
        #pragma unroll
        for (int u = 0; u < 4; ++u) {
            int j0 = m + 2 * u, j1 = j0 + 1;
            uint32_t q0 = cs[(j0 < cnt) ? j0 : cnt - 1];
            uint32_t q1 = cs[(j1 < cnt) ? j1 : cnt - 1];
            if (j0 >= cnt) q0 &= 0xFFFF0000u;   // wave-uniform
            if (j1 >= cnt) q1 &= 0xFFFF0000u;
            uint32_t qv = hiHalf ? q1 : q0;
            uint4 w = *reinterpret_cast<const uint4*>(xwbase + QOFF(qv));
            ACCMIX8(w, qv);
        }
    }
    #undef QOFF

    // cross-half combine: partner lane = lane ^ 32
    a0 += __shfl(a0, lane ^ 32, 64); a1 += __shfl(a1, lane ^ 32, 64);
    a2 += __shfl(a2, lane ^ 32, 64); a3 += __shfl(a3, lane ^ 32, 64);
    a4 += __shfl(a4, lane ^ 32, 64); a5 += __shfl(a5, lane ^ 32, 64);
    a6 += __shfl(a6, lane ^ 32, 64); a7 += __shfl(a7, lane ^ 32, 64);

    float4 o = hiHalf
        ? make_float4(fmaxf(a4, 0.f), fmaxf(a5, 0.f), fmaxf(a6, 0.f), fmaxf(a7, 0.f))
        : make_float4(fmaxf(a0, 0.f), fmaxf(a1, 0.f), fmaxf(a2, 0.f), fmaxf(a3, 0.f));
    float* orow = out + ((size_t)b * NN + n) * COUT + sub * 8 + (hiHalf ? 4 : 0);
    *reinterpret_cast<float4*>(orow) = o;
}

// ---------------- fallback (atomic) path ----------------
__global__ __launch_bounds__(256) void cvt_wt_kernel(const float* __restrict__ W, _Float16* __restrict__ wt) {
    int n = blockIdx.x;
    int k = threadIdx.x;
    wt[n * CIN + k] = (_Float16)W[(size_t)k * COUT + n];
}

__global__ __launch_bounds__(256) void init_deg_kernel(float* __restrict__ deg, float v) {
    int i = blockIdx.x * 256 + threadIdx.x;
    if (i < BB * NN) deg[i] = v;
}

__global__ __launch_bounds__(256) void deg_only_kernel(const int* __restrict__ ei, const float* __restrict__ ew,
                                                       float* __restrict__ deg) {
    int idx = blockIdx.x * 256 + threadIdx.x;
    if (idx >= BB * EE) return;
    int b = idx / EE, e = idx - b * EE;
    atomicAdd(&deg[b * NN + ei[(size_t)b * 2 * EE + e]], ew[(size_t)b * EE + e]);
}

__global__ __launch_bounds__(256) void deginv_kernel(const float* __restrict__ deg, float* __restrict__ dinv) {
    int i = blockIdx.x * 256 + threadIdx.x;
    if (i < BB * NN) {
        float d = deg[i];
        dinv[i] = (d > 0.0f) ? rsqrtf(d) : 0.0f;
    }
}

__global__ __launch_bounds__(256) void self_kernel(const _Float16* __restrict__ xw, const float* __restrict__ dinv,
                                                   float* __restrict__ out) {
    int bn = blockIdx.x;
    int c = threadIdx.x;
    float di = dinv[bn];
    out[(size_t)bn * COUT + c] = di * di * (float)xw[(size_t)bn * COUT + c];
}

__global__ __launch_bounds__(256) void scatter_atomic_kernel(const int* __restrict__ ei, const float* __restrict__ ew,
                                                             const float* __restrict__ dinv,
                                                             const _Float16* __restrict__ xw, float* __restrict__ out) {
    int be = blockIdx.x;
    int b = be / EE, e = be - b * EE;
    int c = threadIdx.x;
    int row = ei[(size_t)b * 2 * EE + e];
    int col = ei[(size_t)b * 2 * EE + EE + e];
    float w = ew[(size_t)b * EE + e];
    float nm = dinv[b * NN + row] * w * dinv[b * NN + col];
    const _Float16* xwb = xw + (size_t)b * NN * COUT;
    atomicAdd(&out[((size_t)b * NN + row) * COUT + c], nm * (float)xwb[(size_t)col * COUT + c]);
}

__global__ __launch_bounds__(256) void relu_kernel(float* __restrict__ out) {
    size_t i = (size_t)blockIdx.x * 256 + threadIdx.x;
    out[i] = fmaxf(out[i], 0.0f);
}

extern "C" void kernel_launch(void* const* d_in, const int* in_sizes, int n_in,
                              void* d_out, int out_size, void* d_ws, size_t ws_size,
                              hipStream_t stream) {
    const float* x  = (const float*)d_in[0];
    const int*   ei = (const int*)d_in[1];
    const float* ew = (const float*)d_in[2];
    const float* Wm = (const float*)d_in[3];
    float* out = (float*)d_out;

    char* ws = (char*)d_ws;
    size_t off = 0;
    auto alloc = [&](size_t bytes) -> void* {
        void* p = ws + off;
        off += (bytes + 255) & ~(size_t)255;
        return p;
    };
    _Float16* xw        = (_Float16*)alloc((size_t)BB * NN * COUT * 2);   // 32 MB
    int*      chist     = (int*)alloc((size_t)BB * NCH * NN * 4);         // 4 MB
    float*    wdeg      = (float*)alloc((size_t)BB * NCH * NN * 4);       // 4 MB (contiguous after chist)
    int*      chunkbase = (int*)alloc((size_t)BB * NCH * NN * 4);         // 4 MB
    int*      roff      = (int*)alloc((size_t)BB * NN * 4);               // 256 KB
    float*    dinv      = (float*)alloc((size_t)BB * NN * 4);             // 256 KB
    _Float16* wt        = (_Float16*)alloc((size_t)CIN * COUT * 2);
    // packed csr (8 MB) aliases chist+wdeg: both dead after scanfused (prior dispatch) -> race-free
    uint32_t* csr       = (uint32_t*)chist;
    float*    deg_fb    = (float*)chist;    // fallback-only alias
    bool use_csr = (ws_size >= off);

    if (use_csr) {
        phaseA_kernel<<<BB * NCH + COUT, 256, 0, stream>>>(Wm, wt, ei, ew, chist, wdeg);
        scanfused_kernel<<<BB, 1024, 0, stream>>>(chist, wdeg, chunkbase, roff, dinv);
        scatter2_kernel<<<BB * NCH, 256, 0, stream>>>(ei, ew, dinv, chunkbase, csr);
        gemm_wide_kernel<<<BB * NN / 128, 512, 0, stream>>>(x, wt, xw);
        aggregate_kernel<<<BB * NN / 4, 256, 0, stream>>>(xw, dinv, roff, csr, out);
    } else {
        const int bnBlocks = (BB * NN) / 256;
        cvt_wt_kernel<<<COUT, CIN, 0, stream>>>(Wm, wt);
        init_deg_kernel<<<bnBlocks, 256, 0, stream>>>(deg_fb, 1.0f);
        deg_only_kernel<<<(BB * EE) / 256, 256, 0, stream>>>(ei, ew, deg_fb);
        deginv_kernel<<<bnBlocks, 256, 0, stream>>>(deg_fb, dinv);
        gemm_wide_kernel<<<BB * NN / 128, 512, 0, stream>>>(x, wt, xw);
        self_kernel<<<BB * NN, 256, 0, stream>>>(xw, dinv, out);
        scatter_atomic_kernel<<<BB * EE, 256, 0, stream>>>(ei, ew, dinv, xw, out);
        relu_kernel<<<(BB * NN * COUT) / 256, 256, 0, stream>>>(out);
    }
}

// Round 19
// 123.073 us; speedup vs baseline: 1.0681x; 1.0681x over previous
//
#include <hip/hip_runtime.h>
#include <cstdint>
#include <cstddef>

#define BB 16
#define NN 4096
#define EE 131072
#define CIN 256
#define COUT 256
#define NCH 16
#define CHE (EE / NCH)   // 8192 edges per chunk

typedef __attribute__((ext_vector_type(8))) _Float16 h16x8;
typedef __attribute__((ext_vector_type(4))) float f32x4;

// ---------------- phase A: hist (blocks 0..255) ∥ W^T->fp16 (256..511) ----------------
__global__ __launch_bounds__(256) void phaseA_kernel(const float* __restrict__ W, _Float16* __restrict__ wt,
                                                     const int* __restrict__ ei, const float* __restrict__ ew,
                                                     int* __restrict__ chist, float* __restrict__ wdeg) {
    __shared__ int h[NN];       // 16 KB
    __shared__ float wh[NN];    // 16 KB
    int bid = blockIdx.x;
    int tid = threadIdx.x;
    if (bid < BB * NCH) {
        int b = bid >> 4, c = bid & (NCH - 1);
        for (int i = tid; i < NN; i += 256) { h[i] = 0; wh[i] = 0.f; }
        __syncthreads();
        const int* rows = ei + (size_t)b * 2 * EE + (size_t)c * CHE;
        const float* w = ew + (size_t)b * EE + (size_t)c * CHE;
        #pragma unroll 4
        for (int j = 0; j < CHE / 256; ++j) {
            int row = rows[j * 256 + tid];
            float wv = w[j * 256 + tid];
            atomicAdd(&h[row], 1);
            atomicAdd(&wh[row], wv);
        }
        __syncthreads();
        int* co = chist + ((size_t)b * NCH + c) * NN;
        float* wo = wdeg + ((size_t)b * NCH + c) * NN;
        for (int i = tid; i < NN; i += 256) { co[i] = h[i]; wo[i] = wh[i]; }
    } else {
        int n = bid - BB * NCH;   // 0..255
        int k = tid;
        wt[n * CIN + k] = (_Float16)W[(size_t)k * COUT + n];
    }
}

// ---------------- fused: row totals + dinv + scan + per-chunk bases (16 blocks) ----------------
__global__ __launch_bounds__(1024) void scanfused_kernel(const int* __restrict__ chist, const float* __restrict__ wdeg,
                                                         int* __restrict__ chunkbase, int* __restrict__ roff,
                                                         float* __restrict__ dinv) {
    int b = blockIdx.x, tid = threadIdx.x;
    int wid = tid >> 6, lane = tid & 63;
    __shared__ int wsum[16];
    __shared__ int wbase[16];
    __shared__ int gtot_s;
    int carry = 0;
    for (int g = 0; g < 4; ++g) {
        int r = g * 1024 + tid;
        int cv[NCH];
        int tot = 0;
        float dsum = 1.0f;   // +1 self loop, always > 0
        #pragma unroll
        for (int c = 0; c < NCH; ++c) {
            size_t idx = ((size_t)b * NCH + c) * NN + r;
            cv[c] = chist[idx];
            tot += cv[c];
            dsum += wdeg[idx];
        }
        dinv[b * NN + r] = rsqrtf(dsum);
        int incl = tot;
        #pragma unroll
        for (int off = 1; off < 64; off <<= 1) {
            int t = __shfl_up(incl, off, 64);
            if (lane >= off) incl += t;
        }
        if (lane == 63) wsum[wid] = incl;
        __syncthreads();
        if (wid == 0) {
            int v = (lane < 16) ? wsum[lane] : 0;
            int winc = v;
            #pragma unroll
            for (int off = 1; off < 16; off <<= 1) {
                int t = __shfl_up(winc, off, 64);
                if (lane >= off) winc += t;
            }
            if (lane < 16) wbase[lane] = winc - v;
            if (lane == 15) gtot_s = winc;
        }
        __syncthreads();
        int excl = carry + wbase[wid] + (incl - tot);
        roff[b * NN + r] = excl;
        int acc = excl;
        #pragma unroll
        for (int c = 0; c < NCH; ++c) {
            chunkbase[((size_t)b * NCH + c) * NN + r] = acc;
            acc += cv[c];
        }
        carry += gtot_s;
        __syncthreads();
    }
}

// ---------------- scatter into packed CSR slots — LDS atomics only, XCD-pinned ----------------
__global__ __launch_bounds__(256) void scatter2_kernel(const int* __restrict__ ei, const float* __restrict__ ew,
                                                       const float* __restrict__ dinv, const int* __restrict__ chunkbase,
                                                       uint32_t* __restrict__ csr) {
    __shared__ int basebuf[NN];     // 16 KB
    __shared__ float dinvs[NN];     // 16 KB
    int bid = blockIdx.x;           // 256 blocks
    int xcd = bid & 7;
    int j = bid >> 3;
    int b = xcd * 2 + (j >> 4);
    int c = j & (NCH - 1);
    int tid = threadIdx.x;
    for (int i = tid; i < NN; i += 256) {
        basebuf[i] = chunkbase[((size_t)b * NCH + c) * NN + i];
        dinvs[i] = dinv[b * NN + i];
    }
    __syncthreads();
    const int* rows = ei + (size_t)b * 2 * EE + (size_t)c * CHE;
    const int* cols = rows + EE;
    const float* w = ew + (size_t)b * EE + (size_t)c * CHE;
    uint32_t* cs = csr + (size_t)b * EE;
    #pragma unroll 4
    for (int jj = 0; jj < CHE / 256; ++jj) {
        int e = jj * 256 + tid;
        int row = rows[e];
        int col = cols[e];
        float nm = dinvs[row] * w[e] * dinvs[col];
        int pos = atomicAdd(&basebuf[row], 1);
        uint32_t nmh = (uint32_t)__builtin_bit_cast(unsigned short, (_Float16)nm);
        cs[pos] = ((uint32_t)col << 16) | nmh;
    }
}

// ---------------- wide MFMA GEMM, 128x256 tile, 512 threads, XOR-swizzled LDS (FROZEN) ----------------
#define SWZ(byte_, row_) ((byte_) ^ (((row_) & 7) << 4))
__global__ __launch_bounds__(512) void gemm_wide_kernel(const float* __restrict__ x, const _Float16* __restrict__ wt,
                                                        _Float16* __restrict__ xw) {
    __shared__ __align__(16) char smem[49152];   // As 16 KB + Bs 32 KB
    char* As = smem;             // [128 rows][64 k] fp16, swizzled
    char* Bs = smem + 16384;     // [256 cols][64 k] fp16, swizzled
    int tid = threadIdx.x;
    int lane = tid & 63;
    int wid = tid >> 6;          // 0..7
    int wr = wid >> 2, wc = wid & 3;   // 2x4 wave grid, each wave 64 rows x 64 cols
    int hi = lane >> 4, lo = lane & 15;
    int row0 = blockIdx.x * 128; // 512 blocks
    f32x4 acc[4][4] = {};

    for (int kk = 0; kk < CIN; kk += 64) {
        #pragma unroll
        for (int j = 0; j < 2; ++j) {
            int c = j * 512 + tid;
            int r = c >> 3, kq = c & 7;
            const float* g = &x[(size_t)(row0 + r) * CIN + kk + 8 * kq];
            float4 f0 = *reinterpret_cast<const float4*>(g);
            float4 f1 = *reinterpret_cast<const float4*>(g + 4);
            h16x8 v;
            v[0] = (_Float16)f0.x; v[1] = (_Float16)f0.y; v[2] = (_Float16)f0.z; v[3] = (_Float16)f0.w;
            v[4] = (_Float16)f1.x; v[5] = (_Float16)f1.y; v[6] = (_Float16)f1.z; v[7] = (_Float16)f1.w;
            *reinterpret_cast<h16x8*>(As + SWZ(r * 128 + kq * 16, r)) = v;
        }
        #pragma unroll
        for (int j = 0; j < 4; ++j) {
            int c = j * 512 + tid;
            int r = c >> 3, kq = c & 7;
            *reinterpret_cast<h16x8*>(Bs + SWZ(r * 128 + kq * 16, r)) =
                *reinterpret_cast<const h16x8*>(&wt[(size_t)r * CIN + kk + 8 * kq]);
        }
        __syncthreads();
        #pragma unroll
        for (int ks = 0; ks < 2; ++ks) {
            h16x8 a[4], b[4];
            #pragma unroll
            for (int m = 0; m < 4; ++m) {
                int r = wr * 64 + m * 16 + lo;
                a[m] = *reinterpret_cast<const h16x8*>(As + SWZ(r * 128 + ks * 64 + hi * 16, r));
            }
            #pragma unroll
            for (int n = 0; n < 4; ++n) {
                int r = wc * 64 + n * 16 + lo;
                b[n] = *reinterpret_cast<const h16x8*>(Bs + SWZ(r * 128 + ks * 64 + hi * 16, r));
            }
            #pragma unroll
            for (int m = 0; m < 4; ++m)
                #pragma unroll
                for (int n = 0; n < 4; ++n)
                    acc[m][n] = __builtin_amdgcn_mfma_f32_16x16x32_f16(a[m], b[n], acc[m][n], 0, 0, 0);
        }
        __syncthreads();
    }
    #pragma unroll
    for (int m = 0; m < 4; ++m)
        #pragma unroll
        for (int n = 0; n < 4; ++n)
            #pragma unroll
            for (int r = 0; r < 4; ++r) {
                int row = row0 + wr * 64 + m * 16 + hi * 4 + r;
                int col = wc * 64 + n * 16 + lo;
                xw[(size_t)row * COUT + col] = (_Float16)acc[m][n][r];
            }
}

// ---------------- CSR aggregation v9r: packed 4B CSR, per-stmt fma_mix (schedulable), and_or addr ----------------
#define MIXQLO(acc_, w_, qv_) asm("v_fma_mix_f32 %0, %1, %2, %0 op_sel:[0,0,0] op_sel_hi:[1,1,0]" \
                                  : "+v"(acc_) : "v"(w_), "v"(qv_));
#define MIXQHI(acc_, w_, qv_) asm("v_fma_mix_f32 %0, %1, %2, %0 op_sel:[1,0,0] op_sel_hi:[1,1,0]" \
                                  : "+v"(acc_) : "v"(w_), "v"(qv_));
#define ACCMIXQ(w_, qv_) { \
    MIXQLO(a0, (w_).x, qv_); MIXQHI(a1, (w_).x, qv_); \
    MIXQLO(a2, (w_).y, qv_); MIXQHI(a3, (w_).y, qv_); \
    MIXQLO(a4, (w_).z, qv_); MIXQHI(a5, (w_).z, qv_); \
    MIXQLO(a6, (w_).w, qv_); MIXQHI(a7, (w_).w, qv_); }
#define MIXSLO(acc_, w_, nm_) asm("v_fma_mix_f32 %0, %1, %2, %0 op_sel:[0,0,0] op_sel_hi:[1,0,0]" \
                                  : "+v"(acc_) : "v"(w_), "v"(nm_));
#define MIXSHI(acc_, w_, nm_) asm("v_fma_mix_f32 %0, %1, %2, %0 op_sel:[1,0,0] op_sel_hi:[1,0,0]" \
                                  : "+v"(acc_) : "v"(w_), "v"(nm_));

__global__ __launch_bounds__(256) void aggregate_kernel(const _Float16* __restrict__ xw, const float* __restrict__ dinv,
                                                        const int* __restrict__ roff, const uint32_t* __restrict__ csr,
                                                        float* __restrict__ out) {
    int bid = blockIdx.x;            // 16384 blocks
    int xcd = bid & 7;
    int idx = bid >> 3;              // 0..2047
    int b = xcd * 2 + (idx >> 10);
    int rowblk = idx & 1023;
    int wave = threadIdx.x >> 6;
    int lane = threadIdx.x & 63;
    int n = rowblk * 4 + wave;       // 1 row per wave
    bool hiHalf = lane >= 32;
    int sub = lane & 31;             // 16B-granule index within row
    uint32_t lanebyte = sub * 16;    // bits 4..8

    const int* rb = roff + b * NN;
    int s = __builtin_amdgcn_readfirstlane(rb[n]);
    int eRaw = (n == NN - 1) ? EE : rb[n + 1];
    int e = __builtin_amdgcn_readfirstlane(eRaw);
    int cnt = e - s;
    const uint32_t* cs = csr + (size_t)b * EE + s;

    const char* xwbase = (const char*)(xw + (size_t)b * NN * COUT);   // wave-uniform base
    float a0 = 0.f, a1 = 0.f, a2 = 0.f, a3 = 0.f, a4 = 0.f, a5 = 0.f, a6 = 0.f, a7 = 0.f;

    {   // self loop (low half applies; high half nm=0, read harmless)
        float di = dinv[b * NN + n];
        float sn = hiHalf ? 0.f : di * di;
        uint4 w = *reinterpret_cast<const uint4*>(xwbase + (size_t)n * (COUT * 2) + lanebyte);
        MIXSLO(a0, w.x, sn); MIXSHI(a1, w.x, sn);
        MIXSLO(a2, w.y, sn); MIXSHI(a3, w.y, sn);
        MIXSLO(a4, w.z, sn); MIXSHI(a5, w.z, sn);
        MIXSLO(a6, w.w, sn); MIXSHI(a7, w.w, sn);
    }

    // addr: col*512 = (qv >> 7) & 0x001FFE00 (bits 9..20); | lanebyte (bits 4..8) disjoint
    #define QOFF(qv_) ((((qv_) >> 7) & 0x001FFE00u) | lanebyte)

    int m = cnt & ~7;
    int i = 0;
    for (; i < m; i += 8) {
        uint32_t q[8];
        #pragma unroll
        for (int u = 0; u < 8; ++u) q[u] = cs[i + u];   // wave-uniform -> scalar s_loads
        #pragma unroll
        for (int u = 0; u < 4; ++u) {
            uint32_t qv = hiHalf ? q[2 * u + 1] : q[2 * u];
            uint4 w = *reinterpret_cast<const uint4*>(xwbase + QOFF(qv));
            ACCMIXQ(w, qv);
        }
    }
    if (i < cnt) {   // 1..7 remaining; pad with zeroed norm (clamped col keeps read in-bounds)
        #pragma unroll
        for (int u = 0; u < 4; ++u) {
            int j0 = i + 2 * u, j1 = j0 + 1;
            uint32_t q0 = cs[(j0 < cnt) ? j0 : cnt - 1];
            uint32_t q1 = cs[(j1 < cnt) ? j1 : cnt - 1];
            if (j0 >= cnt) q0 &= 0xFFFF0000u;   // wave-uniform
            if (j1 >= cnt) q1 &= 0xFFFF0000u;
            uint32_t qv = hiHalf ? q1 : q0;
            uint4 w = *reinterpret_cast<const uint4*>(xwbase + QOFF(qv));
            ACCMIXQ(w, qv);
        }
    }
    #undef QOFF

    // cross-half combine: partner lane = lane ^ 32
    a0 += __shfl(a0, lane ^ 32, 64); a1 += __shfl(a1, lane ^ 32, 64);
    a2 += __shfl(a2, lane ^ 32, 64); a3 += __shfl(a3, lane ^ 32, 64);
    a4 += __shfl(a4, lane ^ 32, 64); a5 += __shfl(a5, lane ^ 32, 64);
    a6 += __shfl(a6, lane ^ 32, 64); a7 += __shfl(a7, lane ^ 32, 64);

    float4 o = hiHalf
        ? make_float4(fmaxf(a4, 0.f), fmaxf(a5, 0.f), fmaxf(a6, 0.f), fmaxf(a7, 0.f))
        : make_float4(fmaxf(a0, 0.f), fmaxf(a1, 0.f), fmaxf(a2, 0.f), fmaxf(a3, 0.f));
    float* orow = out + ((size_t)b * NN + n) * COUT + sub * 8 + (hiHalf ? 4 : 0);
    *reinterpret_cast<float4*>(orow) = o;
}

// ---------------- fallback (atomic) path ----------------
__global__ __launch_bounds__(256) void cvt_wt_kernel(const float* __restrict__ W, _Float16* __restrict__ wt) {
    int n = blockIdx.x;
    int k = threadIdx.x;
    wt[n * CIN + k] = (_Float16)W[(size_t)k * COUT + n];
}

__global__ __launch_bounds__(256) void init_deg_kernel(float* __restrict__ deg, float v) {
    int i = blockIdx.x * 256 + threadIdx.x;
    if (i < BB * NN) deg[i] = v;
}

__global__ __launch_bounds__(256) void deg_only_kernel(const int* __restrict__ ei, const float* __restrict__ ew,
                                                       float* __restrict__ deg) {
    int idx = blockIdx.x * 256 + threadIdx.x;
    if (idx >= BB * EE) return;
    int b = idx / EE, e = idx - b * EE;
    atomicAdd(&deg[b * NN + ei[(size_t)b * 2 * EE + e]], ew[(size_t)b * EE + e]);
}

__global__ __launch_bounds__(256) void deginv_kernel(const float* __restrict__ deg, float* __restrict__ dinv) {
    int i = blockIdx.x * 256 + threadIdx.x;
    if (i < BB * NN) {
        float d = deg[i];
        dinv[i] = (d > 0.0f) ? rsqrtf(d) : 0.0f;
    }
}

__global__ __launch_bounds__(256) void self_kernel(const _Float16* __restrict__ xw, const float* __restrict__ dinv,
                                                   float* __restrict__ out) {
    int bn = blockIdx.x;
    int c = threadIdx.x;
    float di = dinv[bn];
    out[(size_t)bn * COUT + c] = di * di * (float)xw[(size_t)bn * COUT + c];
}

__global__ __launch_bounds__(256) void scatter_atomic_kernel(const int* __restrict__ ei, const float* __restrict__ ew,
                                                             const float* __restrict__ dinv,
                                                             const _Float16* __restrict__ xw, float* __restrict__ out) {
    int be = blockIdx.x;
    int b = be / EE, e = be - b * EE;
    int c = threadIdx.x;
    int row = ei[(size_t)b * 2 * EE + e];
    int col = ei[(size_t)b * 2 * EE + EE + e];
    float w = ew[(size_t)b * EE + e];
    float nm = dinv[b * NN + row] * w * dinv[b * NN + col];
    const _Float16* xwb = xw + (size_t)b * NN * COUT;
    atomicAdd(&out[((size_t)b * NN + row) * COUT + c], nm * (float)xwb[(size_t)col * COUT + c]);
}

__global__ __launch_bounds__(256) void relu_kernel(float* __restrict__ out) {
    size_t i = (size_t)blockIdx.x * 256 + threadIdx.x;
    out[i] = fmaxf(out[i], 0.0f);
}

extern "C" void kernel_launch(void* const* d_in, const int* in_sizes, int n_in,
                              void* d_out, int out_size, void* d_ws, size_t ws_size,
                              hipStream_t stream) {
    const float* x  = (const float*)d_in[0];
    const int*   ei = (const int*)d_in[1];
    const float* ew = (const float*)d_in[2];
    const float* Wm = (const float*)d_in[3];
    float* out = (float*)d_out;

    char* ws = (char*)d_ws;
    size_t off = 0;
    auto alloc = [&](size_t bytes) -> void* {
        void* p = ws + off;
        off += (bytes + 255) & ~(size_t)255;
        return p;
    };
    _Float16* xw        = (_Float16*)alloc((size_t)BB * NN * COUT * 2);   // 32 MB
    int*      chist     = (int*)alloc((size_t)BB * NCH * NN * 4);         // 4 MB
    float*    wdeg      = (float*)alloc((size_t)BB * NCH * NN * 4);       // 4 MB (contiguous after chist)
    int*      chunkbase = (int*)alloc((size_t)BB * NCH * NN * 4);         // 4 MB
    int*      roff      = (int*)alloc((size_t)BB * NN * 4);               // 256 KB
    float*    dinv      = (float*)alloc((size_t)BB * NN * 4);             // 256 KB
    _Float16* wt        = (_Float16*)alloc((size_t)CIN * COUT * 2);
    // packed csr (8 MB) aliases chist+wdeg: both dead after scanfused (prior dispatch) -> race-free
    uint32_t* csr       = (uint32_t*)chist;
    float*    deg_fb    = (float*)chist;    // fallback-only alias
    bool use_csr = (ws_size >= off);

    if (use_csr) {
        phaseA_kernel<<<BB * NCH + COUT, 256, 0, stream>>>(Wm, wt, ei, ew, chist, wdeg);
        scanfused_kernel<<<BB, 1024, 0, stream>>>(chist, wdeg, chunkbase, roff, dinv);
        scatter2_kernel<<<BB * NCH, 256, 0, stream>>>(ei, ew, dinv, chunkbase, csr);
        gemm_wide_kernel<<<BB * NN / 128, 512, 0, stream>>>(x, wt, xw);
        aggregate_kernel<<<BB * NN / 4, 256, 0, stream>>>(xw, dinv, roff, csr, out);
    } else {
        const int bnBlocks = (BB * NN) / 256;
        cvt_wt_kernel<<<COUT, CIN, 0, stream>>>(Wm, wt);
        init_deg_kernel<<<bnBlocks, 256, 0, stream>>>(deg_fb, 1.0f);
        deg_only_kernel<<<(BB * EE) / 256, 256, 0, stream>>>(ei, ew, deg_fb);
        deginv_kernel<<<bnBlocks, 256, 0, stream>>>(deg_fb, dinv);
        gemm_wide_kernel<<<BB * NN / 128, 512, 0, stream>>>(x, wt, xw);
        self_kernel<<<BB * NN, 256, 0, stream>>>(xw, dinv, out);
        scatter_atomic_kernel<<<BB * EE, 256, 0, stream>>>(ei, ew, dinv, xw, out);
        relu_kernel<<<(BB * NN * COUT) / 256, 256, 0, stream>>>(out);
    }
}